// Round 3
// baseline (120.627 us; speedup 1.0000x reference)
//
#include <hip/hip_runtime.h>
#include <hip/hip_bf16.h>

// Problem constants (fixed by the reference)
#define BATCH 8
#define NPTS  4096      // N
#define CCH   128      // C
#define KNN_K 16       // K

typedef __attribute__((ext_vector_type(8))) short  bf16x8;  // 8 bf16 = 4 VGPRs
typedef __attribute__((ext_vector_type(4))) float  f32x4;   // MFMA acc

// ---------------------------------------------------------------------------
// ws layout (bytes):
//   [0)          xTb   : B*N*C bf16      = 8,388,608
//   [8388608)    Wb    : C*C  bf16       =    32,768
//   [8421376)    scale : C fp32          =       512
//   [8421888)    bias  : C fp32          =       512
//   [8422400)    pts   : B*N float4(x,y,z,s) = 524,288
//   [8946688)    knn   : B*N*K u16       = 1,048,576
//   [9995264)    Zb    : B*N*C bf16      = 8,388,608   (Z = W@x, [B,N,C])
// total 18,383,872
// ---------------------------------------------------------------------------

static __device__ __forceinline__ short f2bf(float v) {
    __hip_bfloat16 h = __float2bfloat16(v);   // RNE
    return __builtin_bit_cast(short, h);
}

// LDS-tiled transpose: x [B,C,N] fp32 -> xTb [B,N,C] bf16.
__global__ __launch_bounds__(256) void transpose_kernel(
    const float* __restrict__ x, short* __restrict__ xTb)
{
    __shared__ short tile[64 * 66];
    const int tid = threadIdx.x;
    const int b   = blockIdx.x >> 7;         // 8 batches
    const int rem = blockIdx.x & 127;
    const int nt  = rem >> 1;                // 64 n-tiles of 64
    const int ct  = rem & 1;                 // 2 c-tiles of 64

    #pragma unroll
    for (int it = 0; it < 16; ++it) {
        const int idx = it * 256 + tid;
        const int cc  = idx >> 6;
        const int nn  = idx & 63;
        const float v = x[(size_t)(b * CCH + ct * 64 + cc) * NPTS + nt * 64 + nn];
        tile[cc * 66 + nn] = f2bf(v);
    }
    __syncthreads();
    #pragma unroll
    for (int it = 0; it < 16; ++it) {
        const int idx = it * 256 + tid;
        const int nn  = idx >> 6;
        const int cc  = idx & 63;
        xTb[(size_t)(b * NPTS + nt * 64 + nn) * CCH + ct * 64 + cc] = tile[cc * 66 + nn];
    }
}

// Small prep: W -> bf16; fold BN affine; xyz -> SoA float4 with |p|^2
__global__ __launch_bounds__(256) void small_prep_kernel(
    const float* __restrict__ xyz, const float* __restrict__ W,
    const float* __restrict__ gamma, const float* __restrict__ beta,
    const float* __restrict__ rmean, const float* __restrict__ rvar,
    short* __restrict__ Wb, float* __restrict__ scale, float* __restrict__ bias,
    float4* __restrict__ pts)
{
    const int t = blockIdx.x * 256 + threadIdx.x;   // grid covers B*N = 32768
    if (t < CCH * CCH) Wb[t] = f2bf(W[t]);
    if (t < CCH) {
        const float s = gamma[t] / sqrtf(rvar[t] + 1e-5f);
        scale[t] = s;
        bias[t]  = beta[t] - rmean[t] * s;
    }
    {
        #pragma clang fp contract(off)
        const float px = xyz[3 * t + 0];
        const float py = xyz[3 * t + 1];
        const float pz = xyz[3 * t + 2];
        const float s  = px * px + py * py + pz * pz;   // matches ref s = sum(xyz*xyz)
        pts[t] = make_float4(px, py, pz, s);
    }
}

#define PK_(h, l) ((((unsigned long long)(h)) << 32) | (unsigned long long)(l))

// KNN v4 body: buffered top-k with bitonic flush (see R2/v3 comments for the
// invariants). Changes vs v3:
//  - manual A/C double-buffered candidate registers (no rotation moves, no
//    last-iteration prefetch select)
//  - block 0 special case: the first 16 candidates (j = s) are bitonic-sorted
//    directly into the list (kills the tau=inf warm-up appends/flushes)
// Selection semantics == reference top_k: 16 smallest by (d2, j) lex,
// emitted in lex order. Exactness argument unchanged from v3.
static __device__ __forceinline__ void knn_body(
    const int bid, const int tid,
    const float4* __restrict__ pts, unsigned short* __restrict__ knn)
{
    const int lane = tid & 63;
    const int wid  = tid >> 6;
    const int g    = lane >> 4;                 // group (query) 0..3
    const int s    = lane & 15;                 // slot within group
    const int wq   = bid * 16 + wid * 4;        // first query of this wave
    const int b    = wq >> 12;                  // 4 queries never cross a batch
    const int i    = (wq & 4095) + g;           // this lane's query
    const float4* pb = pts + (b << 12);

    const float4 q = pb[i];                     // group-uniform

    const unsigned SENT_HI = 0xFF7FFFFFu;       // mono(+3.4e38)
    const unsigned SENT_LO = 0xFFFFFFFFu;

    unsigned lhi = SENT_HI, llo = SENT_LO;      // sorted top-16 list (asc)
    float bufD = 0.f;                           // survivor buffer (slot s)
    int   bufJ = 0;
    int   cnt  = 0;                             // valid entries (group-uniform)
    float tau  = 3.4e38f;
    const int gsh = g << 4;

    // ascending bitonic sort of (hi,lo) keys across the 16 group lanes
    auto sort16 = [&](unsigned& hi, unsigned& lo) {
        #define CE_(K, J, OFF) { \
            const unsigned ohi = (unsigned)__builtin_amdgcn_ds_swizzle((int)hi, OFF); \
            const unsigned olo = (unsigned)__builtin_amdgcn_ds_swizzle((int)lo, OFF); \
            const bool olt = PK_(ohi, olo) < PK_(hi, lo); \
            const bool sel = (((s & (J)) == 0) == ((s & (K)) == 0)); \
            const bool tk  = sel ? olt : !olt; \
            hi = tk ? ohi : hi; lo = tk ? olo : lo; }
        CE_(2, 1, 0x041F)
        CE_(4, 2, 0x081F)  CE_(4, 1, 0x041F)
        CE_(8, 4, 0x101F)  CE_(8, 2, 0x081F)  CE_(8, 1, 0x041F)
        CE_(16, 8, 0x201F) CE_(16, 4, 0x101F) CE_(16, 2, 0x081F) CE_(16, 1, 0x041F)
        #undef CE_
    };

    // tau = inv-mono(list[15].hi)  (broadcast slot 15 within each 16-group)
    auto refresh_tau = [&]() {
        const unsigned thi = (unsigned)__builtin_amdgcn_ds_swizzle((int)lhi, 0x01F0);
        tau = __uint_as_float((thi & 0x80000000u) ? (thi & 0x7FFFFFFFu) : ~thi);
    };

    auto flush = [&]() {
        // build keys from buffer; invalid slots -> sentinel
        const unsigned u = __float_as_uint(bufD);
        unsigned khi = (u & 0x80000000u) ? ~u : (u | 0x80000000u);
        unsigned klo = (unsigned)bufJ;
        const bool inval = (s >= cnt);
        khi = inval ? SENT_HI : khi;
        klo = inval ? SENT_LO : klo;
        sort16(khi, klo);
        // merge with list: reverse buffer, elementwise min, 4 clean stages
        {
            const unsigned rhi = (unsigned)__builtin_amdgcn_ds_swizzle((int)khi, 0x3C1F);
            const unsigned rlo = (unsigned)__builtin_amdgcn_ds_swizzle((int)klo, 0x3C1F);
            const bool rlt = PK_(rhi, rlo) < PK_(lhi, llo);
            lhi = rlt ? rhi : lhi; llo = rlt ? rlo : llo;
        }
        #define MC_(J, OFF) { \
            const unsigned ohi = (unsigned)__builtin_amdgcn_ds_swizzle((int)lhi, OFF); \
            const unsigned olo = (unsigned)__builtin_amdgcn_ds_swizzle((int)llo, OFF); \
            const bool olt = PK_(ohi, olo) < PK_(lhi, llo); \
            const bool tk  = ((s & (J)) == 0) ? olt : !olt; \
            lhi = tk ? ohi : lhi; llo = tk ? olo : llo; }
        MC_(8, 0x201F) MC_(4, 0x101F) MC_(2, 0x081F) MC_(1, 0x041F)
        #undef MC_
        refresh_tau();
        cnt = 0;
    };

    // filter + parallel append for one 16-candidate sub-chunk
    #define SUB_(DD, C, JB) { \
        const unsigned long long mask = __ballot((DD) < tau); \
        if (mask) { \
            const unsigned sub = (unsigned)((mask >> gsh) & 0xFFFFull); \
            const int m = __popc(sub); \
            if (__any(cnt + m > 15)) flush(); \
            const bool surv = (sub >> s) & 1u; \
            const int rank  = __popc(sub & ((1u << s) - 1u)); \
            const int dest  = surv ? (cnt + rank) : 15;   /* slot 15 free when m<16 */ \
            const int addr  = (gsh | dest) << 2; \
            const int nd = __builtin_amdgcn_ds_permute(addr, __float_as_int(DD)); \
            const int nj = __builtin_amdgcn_ds_permute(addr, (JB) + ((C) << 4) + s); \
            const bool got = (s >= cnt) & (s < cnt + m); \
            bufD = got ? __int_as_float(nd) : bufD; \
            bufJ = got ? nj : bufJ; \
            cnt += m; \
        } }

    // process one 64-candidate block (4 sub-chunks of 16)
    auto process = [&](const float4& p0, const float4& p1,
                       const float4& p2, const float4& p3, const int jbase) {
        float dd0, dd1, dd2, dd3;
        {
            #pragma clang fp contract(off)
            dd0 = (q.w + p0.w) - 2.0f * (q.x * p0.x + q.y * p0.y + q.z * p0.z);
            dd1 = (q.w + p1.w) - 2.0f * (q.x * p1.x + q.y * p1.y + q.z * p1.z);
            dd2 = (q.w + p2.w) - 2.0f * (q.x * p2.x + q.y * p2.y + q.z * p2.z);
            dd3 = (q.w + p3.w) - 2.0f * (q.x * p3.x + q.y * p3.y + q.z * p3.z);
        }
        SUB_(dd0, 0, jbase)
        SUB_(dd1, 1, jbase)
        SUB_(dd2, 2, jbase)
        SUB_(dd3, 3, jbase)
    };

    const float4* lp = pb + s;
    // block 0 into A, block 1 into C
    float4 a0 = lp[0],  a1 = lp[16],  a2 = lp[32],  a3 = lp[48];
    float4 c0 = lp[64], c1 = lp[80],  c2 = lp[96],  c3 = lp[112];

    // ---- special block 0: sort first sub-chunk (j = s) directly into list
    {
        float dd0, dd1, dd2, dd3;
        {
            #pragma clang fp contract(off)
            dd0 = (q.w + a0.w) - 2.0f * (q.x * a0.x + q.y * a0.y + q.z * a0.z);
            dd1 = (q.w + a1.w) - 2.0f * (q.x * a1.x + q.y * a1.y + q.z * a1.z);
            dd2 = (q.w + a2.w) - 2.0f * (q.x * a2.x + q.y * a2.y + q.z * a2.z);
            dd3 = (q.w + a3.w) - 2.0f * (q.x * a3.x + q.y * a3.y + q.z * a3.z);
        }
        const unsigned u = __float_as_uint(dd0);
        lhi = (u & 0x80000000u) ? ~u : (u | 0x80000000u);
        llo = (unsigned)s;                      // j = s for sub-chunk 0
        sort16(lhi, llo);
        refresh_tau();
        SUB_(dd1, 1, 0)
        SUB_(dd2, 2, 0)
        SUB_(dd3, 3, 0)
    }

    // ---- main loop: blocks 1..62 double-buffered, 63 peeled
    #pragma unroll 1
    for (int t = 0; t < 31; ++t) {
        const int blk = 1 + 2 * t;              // C holds block blk
        const float4* p2 = lp + (blk + 1) * 64; // prefetch blk+1 into A
        a0 = p2[0]; a1 = p2[16]; a2 = p2[32]; a3 = p2[48];
        process(c0, c1, c2, c3, blk * 64);
        const float4* p3 = lp + (blk + 2) * 64; // prefetch blk+2 into C (max 63)
        c0 = p3[0]; c1 = p3[16]; c2 = p3[32]; c3 = p3[48];
        process(a0, a1, a2, a3, (blk + 1) * 64);
    }
    process(c0, c1, c2, c3, 63 * 64);           // C holds block 63
    #undef SUB_

    flush();                                    // drain remaining buffer

    unsigned short* o = knn + ((((size_t)b << 12) + i) << 4);
    o[s] = (unsigned short)llo;                 // j of s-th smallest (d2, j)
}

// Dense GEMM body (LDS-free): Z[g, c] = sum_k xTb[g, k] * W[c, k].
// W (32 KB) is L1/L2-resident; fragments read directly from global so knn
// blocks in the fused kernel pay no LDS. Verified fragment mappings
// unchanged (A: m=lane&15, k=(lane>>4)*8+j; B: n=lane&15; C/D: col=lane&15,
// row=(lane>>4)*4+reg).
static __device__ __forceinline__ void zgemm_body(
    const int bid, const int tid,
    const short* __restrict__ xTb, const short* __restrict__ Wb,
    short* __restrict__ Zb)
{
    const int lane = tid & 63;
    const int wid  = tid >> 6;
    const int kl   = lane & 15;
    const int q8   = (lane >> 4) * 8;

    const int    G    = bid * 64 + wid * 16 + kl;   // A-row (flat B*N)
    const size_t arow = (size_t)G * CCH;

    const f32x4 zero = {0.f, 0.f, 0.f, 0.f};
    f32x4 acc[8];
    #pragma unroll
    for (int t = 0; t < 8; ++t) acc[t] = zero;

    #pragma unroll 1
    for (int kk = 0; kk < 4; ++kk) {
        const bf16x8 a = *(const bf16x8*)(xTb + arow + kk * 32 + q8);
        #pragma unroll 2
        for (int t = 0; t < 8; ++t) {
            const bf16x8 bf = *(const bf16x8*)(Wb + (t * 16 + kl) * CCH + kk * 32 + q8);
            acc[t] = __builtin_amdgcn_mfma_f32_16x16x32_bf16(a, bf, acc[t], 0, 0, 0);
        }
    }

    const int rbase = bid * 64 + wid * 16 + (lane >> 4) * 4;
    #pragma unroll
    for (int t = 0; t < 8; ++t)
        #pragma unroll
        for (int r = 0; r < 4; ++r)
            Zb[(size_t)(rbase + r) * CCH + t * 16 + kl] = f2bf(acc[t][r]);
}

// Fused heterogeneous dispatch: 2560 blocks = 2048 knn + 512 zgemm,
// interleaved (every 5th block is zgemm) so both kinds are co-resident from
// the start. knn is VALU-bound, zgemm is MFMA/VMEM-bound -> disjoint pipes
// overlap. __launch_bounds__(256,8) pins VGPR <= 64 so knn keeps 8 waves/SIMD.
__global__ __launch_bounds__(256, 8) void knn_zgemm_kernel(
    const float4* __restrict__ pts, unsigned short* __restrict__ knn,
    const short* __restrict__ xTb, const short* __restrict__ Wb,
    short* __restrict__ Zb)
{
    const int bid = blockIdx.x;
    const int qd  = bid / 5;
    const int rm  = bid - qd * 5;
    if (rm == 4) {
        zgemm_body(qd, threadIdx.x, xTb, Wb, Zb);
    } else {
        knn_body(qd * 4 + rm, threadIdx.x, pts, knn);
    }
}

// Gather + BN + ReLU + max-over-16, then coalesced store via LDS transpose.
// Block = 16 points; wave w handles 4 points serially; lane l covers channels
// 2l, 2l+1 (one dword per Z-row read; full 256B row per wave, coalesced).
__global__ __launch_bounds__(256) void gmax_kernel(
    const short* __restrict__ Zb, const unsigned short* __restrict__ knn,
    const float* __restrict__ scale, const float* __restrict__ bias,
    float* __restrict__ out)
{
    __shared__ float sm[16][132];
    const int lane = threadIdx.x & 63;
    const int wid  = threadIdx.x >> 6;
    const int n0   = blockIdx.x * 16;           // flat point base (B*N)
    const int b    = blockIdx.x >> 8;           // 256 blocks per batch
    const float s0 = scale[2 * lane],   s1 = scale[2 * lane + 1];
    const float t0 = bias[2 * lane],    t1 = bias[2 * lane + 1];

    for (int p = 0; p < 4; ++p) {
        const int n = n0 + wid * 4 + p;         // flat
        const unsigned short* kr = knn + (size_t)n * 16;
        float m0 = 0.f, m1 = 0.f;               // relu floor
        #pragma unroll
        for (int k = 0; k < 16; ++k) {
            const int r = (int)kr[k];           // within-batch row
            const unsigned v = *(const unsigned*)(Zb + ((size_t)(b * NPTS + r)) * CCH + 2 * lane);
            const float z0 = __uint_as_float(v << 16);
            const float z1 = __uint_as_float(v & 0xFFFF0000u);
            m0 = fmaxf(m0, s0 * z0 + t0);
            m1 = fmaxf(m1, s1 * z1 + t1);
        }
        sm[wid * 4 + p][2 * lane]     = m0;
        sm[wid * 4 + p][2 * lane + 1] = m1;
    }
    __syncthreads();

    const int c    = threadIdx.x & 127;
    const int half = threadIdx.x >> 7;
    float v[8];
    #pragma unroll
    for (int i = 0; i < 8; ++i) v[i] = sm[half * 8 + i][c];
    float4 f0 = {v[0], v[1], v[2], v[3]};
    float4 f1 = {v[4], v[5], v[6], v[7]};
    float* op = out + ((size_t)(b * CCH + c)) * NPTS + (n0 & 4095) + half * 8;
    *(float4*)op       = f0;
    *(float4*)(op + 4) = f1;
}

extern "C" void kernel_launch(void* const* d_in, const int* in_sizes, int n_in,
                              void* d_out, int out_size, void* d_ws, size_t ws_size,
                              hipStream_t stream)
{
    const float* xyz   = (const float*)d_in[0];
    const float* x     = (const float*)d_in[1];
    const float* W     = (const float*)d_in[2];
    const float* gamma = (const float*)d_in[3];
    const float* beta  = (const float*)d_in[4];
    const float* rmean = (const float*)d_in[5];
    const float* rvar  = (const float*)d_in[6];
    float* out = (float*)d_out;

    char* ws = (char*)d_ws;
    short*          xTb   = (short*)(ws);
    short*          Wb    = (short*)(ws + 8388608);
    float*          scale = (float*)(ws + 8421376);
    float*          bias  = (float*)(ws + 8421888);
    float4*         pts   = (float4*)(ws + 8422400);
    unsigned short* knn   = (unsigned short*)(ws + 8946688);
    short*          Zb    = (short*)(ws + 9995264);

    transpose_kernel<<<BATCH * 64 * 2, 256, 0, stream>>>(x, xTb);
    small_prep_kernel<<<BATCH * NPTS / 256, 256, 0, stream>>>(
        xyz, W, gamma, beta, rmean, rvar, Wb, scale, bias, pts);
    knn_zgemm_kernel<<<BATCH * NPTS / 16 + BATCH * NPTS / 64, 256, 0, stream>>>(
        pts, knn, xTb, Wb, Zb);
    gmax_kernel<<<BATCH * NPTS / 16, 256, 0, stream>>>(Zb, knn, scale, bias, out);
}

// Round 4
// 112.858 us; speedup vs baseline: 1.0688x; 1.0688x over previous
//
#include <hip/hip_runtime.h>
#include <hip/hip_bf16.h>

// Problem constants (fixed by the reference)
#define BATCH 8
#define NPTS  4096      // N
#define CCH   128      // C
#define KNN_K 16       // K

typedef __attribute__((ext_vector_type(8))) short  bf16x8;  // 8 bf16 = 4 VGPRs
typedef __attribute__((ext_vector_type(4))) float  f32x4;   // MFMA acc

// ---------------------------------------------------------------------------
// ws layout (bytes):
//   [0)          xTb   : B*N*C bf16      = 8,388,608
//   [8388608)    Wb    : C*C  bf16       =    32,768
//   [8421376)    scale : C fp32          =       512
//   [8421888)    bias  : C fp32          =       512
//   [8422400)    pts   : B*N float4(x,y,z,s) = 524,288
//   [8946688)    knn   : B*N*K u16       = 1,048,576
//   [9995264)    Zb    : B*N*C bf16      = 8,388,608   (Z = W@x, [B,N,C])
// total 18,383,872
// ---------------------------------------------------------------------------

static __device__ __forceinline__ short f2bf(float v) {
    __hip_bfloat16 h = __float2bfloat16(v);   // RNE
    return __builtin_bit_cast(short, h);
}

// LDS-tiled transpose: x [B,C,N] fp32 -> xTb [B,N,C] bf16.
__global__ __launch_bounds__(256) void transpose_kernel(
    const float* __restrict__ x, short* __restrict__ xTb)
{
    __shared__ short tile[64 * 66];
    const int tid = threadIdx.x;
    const int b   = blockIdx.x >> 7;         // 8 batches
    const int rem = blockIdx.x & 127;
    const int nt  = rem >> 1;                // 64 n-tiles of 64
    const int ct  = rem & 1;                 // 2 c-tiles of 64

    #pragma unroll
    for (int it = 0; it < 16; ++it) {
        const int idx = it * 256 + tid;
        const int cc  = idx >> 6;
        const int nn  = idx & 63;
        const float v = x[(size_t)(b * CCH + ct * 64 + cc) * NPTS + nt * 64 + nn];
        tile[cc * 66 + nn] = f2bf(v);
    }
    __syncthreads();
    #pragma unroll
    for (int it = 0; it < 16; ++it) {
        const int idx = it * 256 + tid;
        const int nn  = idx >> 6;
        const int cc  = idx & 63;
        xTb[(size_t)(b * NPTS + nt * 64 + nn) * CCH + ct * 64 + cc] = tile[cc * 66 + nn];
    }
}

// Small prep: W -> bf16; fold BN affine; xyz -> SoA float4 with |p|^2
__global__ __launch_bounds__(256) void small_prep_kernel(
    const float* __restrict__ xyz, const float* __restrict__ W,
    const float* __restrict__ gamma, const float* __restrict__ beta,
    const float* __restrict__ rmean, const float* __restrict__ rvar,
    short* __restrict__ Wb, float* __restrict__ scale, float* __restrict__ bias,
    float4* __restrict__ pts)
{
    const int t = blockIdx.x * 256 + threadIdx.x;   // grid covers B*N = 32768
    if (t < CCH * CCH) Wb[t] = f2bf(W[t]);
    if (t < CCH) {
        const float s = gamma[t] / sqrtf(rvar[t] + 1e-5f);
        scale[t] = s;
        bias[t]  = beta[t] - rmean[t] * s;
    }
    {
        #pragma clang fp contract(off)
        const float px = xyz[3 * t + 0];
        const float py = xyz[3 * t + 1];
        const float pz = xyz[3 * t + 2];
        const float s  = px * px + py * py + pz * pz;   // matches ref s = sum(xyz*xyz)
        pts[t] = make_float4(px, py, pz, s);
    }
}

#define PK_(h, l) ((((unsigned long long)(h)) << 32) | (unsigned long long)(l))

// KNN v4 (standalone — R3 showed fusing with zgemm thrashes L1 and costs
// more than the overlap saves). Buffered top-k with bitonic flush:
//  - manual A/C double-buffered candidate registers (no rotation moves)
//  - block 0 special case: first 16 candidates bitonic-sorted directly
//    into the list (kills tau=inf warm-up appends/flushes)
// Selection semantics == reference top_k: 16 smallest by (d2, j) lex,
// emitted in lex order. See R2 comments for the exactness argument.
__global__ __launch_bounds__(256) void knn_kernel(
    const float4* __restrict__ pts, unsigned short* __restrict__ knn)
{
    const int lane = threadIdx.x & 63;
    const int wid  = threadIdx.x >> 6;
    const int g    = lane >> 4;                 // group (query) 0..3
    const int s    = lane & 15;                 // slot within group
    const int wq   = blockIdx.x * 16 + wid * 4; // first query of this wave
    const int b    = wq >> 12;                  // 4 queries never cross a batch
    const int i    = (wq & 4095) + g;           // this lane's query
    const float4* pb = pts + (b << 12);

    const float4 q = pb[i];                     // group-uniform

    const unsigned SENT_HI = 0xFF7FFFFFu;       // mono(+3.4e38)
    const unsigned SENT_LO = 0xFFFFFFFFu;

    unsigned lhi = SENT_HI, llo = SENT_LO;      // sorted top-16 list (asc)
    float bufD = 0.f;                           // survivor buffer (slot s)
    int   bufJ = 0;
    int   cnt  = 0;                             // valid entries (group-uniform)
    float tau  = 3.4e38f;
    const int gsh = g << 4;

    // ascending bitonic sort of (hi,lo) keys across the 16 group lanes
    auto sort16 = [&](unsigned& hi, unsigned& lo) {
        #define CE_(K, J, OFF) { \
            const unsigned ohi = (unsigned)__builtin_amdgcn_ds_swizzle((int)hi, OFF); \
            const unsigned olo = (unsigned)__builtin_amdgcn_ds_swizzle((int)lo, OFF); \
            const bool olt = PK_(ohi, olo) < PK_(hi, lo); \
            const bool sel = (((s & (J)) == 0) == ((s & (K)) == 0)); \
            const bool tk  = sel ? olt : !olt; \
            hi = tk ? ohi : hi; lo = tk ? olo : lo; }
        CE_(2, 1, 0x041F)
        CE_(4, 2, 0x081F)  CE_(4, 1, 0x041F)
        CE_(8, 4, 0x101F)  CE_(8, 2, 0x081F)  CE_(8, 1, 0x041F)
        CE_(16, 8, 0x201F) CE_(16, 4, 0x101F) CE_(16, 2, 0x081F) CE_(16, 1, 0x041F)
        #undef CE_
    };

    // tau = inv-mono(list[15].hi)  (broadcast slot 15 within each 16-group)
    auto refresh_tau = [&]() {
        const unsigned thi = (unsigned)__builtin_amdgcn_ds_swizzle((int)lhi, 0x01F0);
        tau = __uint_as_float((thi & 0x80000000u) ? (thi & 0x7FFFFFFFu) : ~thi);
    };

    auto flush = [&]() {
        // build keys from buffer; invalid slots -> sentinel
        const unsigned u = __float_as_uint(bufD);
        unsigned khi = (u & 0x80000000u) ? ~u : (u | 0x80000000u);
        unsigned klo = (unsigned)bufJ;
        const bool inval = (s >= cnt);
        khi = inval ? SENT_HI : khi;
        klo = inval ? SENT_LO : klo;
        sort16(khi, klo);
        // merge with list: reverse buffer, elementwise min, 4 clean stages
        {
            const unsigned rhi = (unsigned)__builtin_amdgcn_ds_swizzle((int)khi, 0x3C1F);
            const unsigned rlo = (unsigned)__builtin_amdgcn_ds_swizzle((int)klo, 0x3C1F);
            const bool rlt = PK_(rhi, rlo) < PK_(lhi, llo);
            lhi = rlt ? rhi : lhi; llo = rlt ? rlo : llo;
        }
        #define MC_(J, OFF) { \
            const unsigned ohi = (unsigned)__builtin_amdgcn_ds_swizzle((int)lhi, OFF); \
            const unsigned olo = (unsigned)__builtin_amdgcn_ds_swizzle((int)llo, OFF); \
            const bool olt = PK_(ohi, olo) < PK_(lhi, llo); \
            const bool tk  = ((s & (J)) == 0) ? olt : !olt; \
            lhi = tk ? ohi : lhi; llo = tk ? olo : llo; }
        MC_(8, 0x201F) MC_(4, 0x101F) MC_(2, 0x081F) MC_(1, 0x041F)
        #undef MC_
        refresh_tau();
        cnt = 0;
    };

    // filter + parallel append for one 16-candidate sub-chunk
    #define SUB_(DD, C, JB) { \
        const unsigned long long mask = __ballot((DD) < tau); \
        if (mask) { \
            const unsigned sub = (unsigned)((mask >> gsh) & 0xFFFFull); \
            const int m = __popc(sub); \
            if (__any(cnt + m > 15)) flush(); \
            const bool surv = (sub >> s) & 1u; \
            const int rank  = __popc(sub & ((1u << s) - 1u)); \
            const int dest  = surv ? (cnt + rank) : 15;   /* slot 15 free when m<16 */ \
            const int addr  = (gsh | dest) << 2; \
            const int nd = __builtin_amdgcn_ds_permute(addr, __float_as_int(DD)); \
            const int nj = __builtin_amdgcn_ds_permute(addr, (JB) + ((C) << 4) + s); \
            const bool got = (s >= cnt) & (s < cnt + m); \
            bufD = got ? __int_as_float(nd) : bufD; \
            bufJ = got ? nj : bufJ; \
            cnt += m; \
        } }

    // process one 64-candidate block (4 sub-chunks of 16)
    auto process = [&](const float4& p0, const float4& p1,
                       const float4& p2, const float4& p3, const int jbase) {
        float dd0, dd1, dd2, dd3;
        {
            #pragma clang fp contract(off)
            dd0 = (q.w + p0.w) - 2.0f * (q.x * p0.x + q.y * p0.y + q.z * p0.z);
            dd1 = (q.w + p1.w) - 2.0f * (q.x * p1.x + q.y * p1.y + q.z * p1.z);
            dd2 = (q.w + p2.w) - 2.0f * (q.x * p2.x + q.y * p2.y + q.z * p2.z);
            dd3 = (q.w + p3.w) - 2.0f * (q.x * p3.x + q.y * p3.y + q.z * p3.z);
        }
        SUB_(dd0, 0, jbase)
        SUB_(dd1, 1, jbase)
        SUB_(dd2, 2, jbase)
        SUB_(dd3, 3, jbase)
    };

    const float4* lp = pb + s;
    // block 0 into A, block 1 into C
    float4 a0 = lp[0],  a1 = lp[16],  a2 = lp[32],  a3 = lp[48];
    float4 c0 = lp[64], c1 = lp[80],  c2 = lp[96],  c3 = lp[112];

    // ---- special block 0: sort first sub-chunk (j = s) directly into list
    {
        float dd0, dd1, dd2, dd3;
        {
            #pragma clang fp contract(off)
            dd0 = (q.w + a0.w) - 2.0f * (q.x * a0.x + q.y * a0.y + q.z * a0.z);
            dd1 = (q.w + a1.w) - 2.0f * (q.x * a1.x + q.y * a1.y + q.z * a1.z);
            dd2 = (q.w + a2.w) - 2.0f * (q.x * a2.x + q.y * a2.y + q.z * a2.z);
            dd3 = (q.w + a3.w) - 2.0f * (q.x * a3.x + q.y * a3.y + q.z * a3.z);
        }
        const unsigned u = __float_as_uint(dd0);
        lhi = (u & 0x80000000u) ? ~u : (u | 0x80000000u);
        llo = (unsigned)s;                      // j = s for sub-chunk 0
        sort16(lhi, llo);
        refresh_tau();
        SUB_(dd1, 1, 0)
        SUB_(dd2, 2, 0)
        SUB_(dd3, 3, 0)
    }

    // ---- main loop: blocks 1..62 double-buffered, 63 peeled
    #pragma unroll 1
    for (int t = 0; t < 31; ++t) {
        const int blk = 1 + 2 * t;              // C holds block blk
        const float4* p2 = lp + (blk + 1) * 64; // prefetch blk+1 into A
        a0 = p2[0]; a1 = p2[16]; a2 = p2[32]; a3 = p2[48];
        process(c0, c1, c2, c3, blk * 64);
        const float4* p3 = lp + (blk + 2) * 64; // prefetch blk+2 into C (max 63)
        c0 = p3[0]; c1 = p3[16]; c2 = p3[32]; c3 = p3[48];
        process(a0, a1, a2, a3, (blk + 1) * 64);
    }
    process(c0, c1, c2, c3, 63 * 64);           // C holds block 63
    #undef SUB_

    flush();                                    // drain remaining buffer

    unsigned short* o = knn + ((((size_t)b << 12) + i) << 4);
    o[s] = (unsigned short)llo;                 // j of s-th smallest (d2, j)
}

// Dense GEMM: Z[g, c] = sum_k xTb[g, k] * W[c, k], Z bf16 [B*N, C].
// Wave = 16 rows x 128 cols; verified fragment mappings (A: m=lane&15,
// k=(lane>>4)*8+j; B: n=lane&15, same k-slice; C/D: col=lane&15,
// row=(lane>>4)*4+reg). W staged in LDS, pitch 136.
__global__ __launch_bounds__(256) void zgemm_kernel(
    const short* __restrict__ xTb, const short* __restrict__ Wb,
    short* __restrict__ Zb)
{
    __shared__ short sW[CCH * 136];
    const int lane = threadIdx.x & 63;
    const int wid  = threadIdx.x >> 6;
    const int kl   = lane & 15;
    const int q8   = (lane >> 4) * 8;

    #pragma unroll
    for (int it = 0; it < 8; ++it) {             // stage W: 16384 elems
        const int e = (it * 256 + threadIdx.x) * 8;
        const int r = e >> 7, c = e & 127;
        *(bf16x8*)(sW + r * 136 + c) = *(const bf16x8*)(Wb + e);
    }

    const int    G    = blockIdx.x * 64 + wid * 16 + kl;   // A-row (flat B*N)
    const size_t arow = (size_t)G * CCH;
    __syncthreads();

    const f32x4 zero = {0.f, 0.f, 0.f, 0.f};
    f32x4 acc[8];
    #pragma unroll
    for (int t = 0; t < 8; ++t) acc[t] = zero;

    #pragma unroll
    for (int kk = 0; kk < 4; ++kk) {
        const bf16x8 a = *(const bf16x8*)(xTb + arow + kk * 32 + q8);
        #pragma unroll
        for (int t = 0; t < 8; ++t) {
            const bf16x8 bf = *(const bf16x8*)(sW + (t * 16 + kl) * 136 + kk * 32 + q8);
            acc[t] = __builtin_amdgcn_mfma_f32_16x16x32_bf16(a, bf, acc[t], 0, 0, 0);
        }
    }

    const int rbase = blockIdx.x * 64 + wid * 16 + (lane >> 4) * 4;
    #pragma unroll
    for (int t = 0; t < 8; ++t)
        #pragma unroll
        for (int r = 0; r < 4; ++r)
            Zb[(size_t)(rbase + r) * CCH + t * 16 + kl] = f2bf(acc[t][r]);
}

// Gather + BN + ReLU + max-over-16, then coalesced store via LDS transpose.
// Block = 16 points; wave w handles 4 points serially; lane l covers channels
// 2l, 2l+1 (one dword per Z-row read; full 256B row per wave, coalesced).
__global__ __launch_bounds__(256) void gmax_kernel(
    const short* __restrict__ Zb, const unsigned short* __restrict__ knn,
    const float* __restrict__ scale, const float* __restrict__ bias,
    float* __restrict__ out)
{
    __shared__ float sm[16][132];
    const int lane = threadIdx.x & 63;
    const int wid  = threadIdx.x >> 6;
    const int n0   = blockIdx.x * 16;           // flat point base (B*N)
    const int b    = blockIdx.x >> 8;           // 256 blocks per batch
    const float s0 = scale[2 * lane],   s1 = scale[2 * lane + 1];
    const float t0 = bias[2 * lane],    t1 = bias[2 * lane + 1];

    for (int p = 0; p < 4; ++p) {
        const int n = n0 + wid * 4 + p;         // flat
        const unsigned short* kr = knn + (size_t)n * 16;
        float m0 = 0.f, m1 = 0.f;               // relu floor
        #pragma unroll
        for (int k = 0; k < 16; ++k) {
            const int r = (int)kr[k];           // within-batch row
            const unsigned v = *(const unsigned*)(Zb + ((size_t)(b * NPTS + r)) * CCH + 2 * lane);
            const float z0 = __uint_as_float(v << 16);
            const float z1 = __uint_as_float(v & 0xFFFF0000u);
            m0 = fmaxf(m0, s0 * z0 + t0);
            m1 = fmaxf(m1, s1 * z1 + t1);
        }
        sm[wid * 4 + p][2 * lane]     = m0;
        sm[wid * 4 + p][2 * lane + 1] = m1;
    }
    __syncthreads();

    const int c    = threadIdx.x & 127;
    const int half = threadIdx.x >> 7;
    float v[8];
    #pragma unroll
    for (int i = 0; i < 8; ++i) v[i] = sm[half * 8 + i][c];
    float4 f0 = {v[0], v[1], v[2], v[3]};
    float4 f1 = {v[4], v[5], v[6], v[7]};
    float* op = out + ((size_t)(b * CCH + c)) * NPTS + (n0 & 4095) + half * 8;
    *(float4*)op       = f0;
    *(float4*)(op + 4) = f1;
}

extern "C" void kernel_launch(void* const* d_in, const int* in_sizes, int n_in,
                              void* d_out, int out_size, void* d_ws, size_t ws_size,
                              hipStream_t stream)
{
    const float* xyz   = (const float*)d_in[0];
    const float* x     = (const float*)d_in[1];
    const float* W     = (const float*)d_in[2];
    const float* gamma = (const float*)d_in[3];
    const float* beta  = (const float*)d_in[4];
    const float* rmean = (const float*)d_in[5];
    const float* rvar  = (const float*)d_in[6];
    float* out = (float*)d_out;

    char* ws = (char*)d_ws;
    short*          xTb   = (short*)(ws);
    short*          Wb    = (short*)(ws + 8388608);
    float*          scale = (float*)(ws + 8421376);
    float*          bias  = (float*)(ws + 8421888);
    float4*         pts   = (float4*)(ws + 8422400);
    unsigned short* knn   = (unsigned short*)(ws + 8946688);
    short*          Zb    = (short*)(ws + 9995264);

    transpose_kernel<<<BATCH * 64 * 2, 256, 0, stream>>>(x, xTb);
    small_prep_kernel<<<BATCH * NPTS / 256, 256, 0, stream>>>(
        xyz, W, gamma, beta, rmean, rvar, Wb, scale, bias, pts);
    knn_kernel<<<BATCH * NPTS / 16, 256, 0, stream>>>(pts, knn);
    zgemm_kernel<<<BATCH * NPTS / 64, 256, 0, stream>>>(xTb, Wb, Zb);
    gmax_kernel<<<BATCH * NPTS / 16, 256, 0, stream>>>(Zb, knn, scale, bias, out);
}